// Round 1
// baseline (5001.525 us; speedup 1.0000x reference)
//
#include <hip/hip_runtime.h>
#include <math.h>

#define NB    16384
#define NDVIS 1024
#define NDH   256
#define NEXP  4
#define NGENE 5000
#define NHID  1024
#define NSCVI 30

__device__ __forceinline__ float gelu_f(float x) {
    return 0.5f * x * (1.0f + erff(x * 0.7071067811865476f));
}
__device__ __forceinline__ float softplus_f(float x) {
    return fmaxf(x, 0.0f) + log1pf(expf(-fabsf(x)));
}
__device__ __forceinline__ float sigmoid_f(float x) {
    return 1.0f / (1.0f + expf(-x));
}

// ---------------------------------------------------------------- fourier
// four[b][j]      = sin(2pi * pos[b] . fB[:,j])   j < 128
// four[b][128+j]  = cos(2pi * pos[b] . fB[:,j])
__global__ __launch_bounds__(256) void k_four(const float* __restrict__ pos,
                                              const float* __restrict__ fB,
                                              float* __restrict__ four) {
    int idx = blockIdx.x * 256 + threadIdx.x;   // b*128 + j
    int b = idx >> 7, j = idx & 127;
    float p0 = pos[b * 3 + 0], p1 = pos[b * 3 + 1], p2 = pos[b * 3 + 2];
    float xp = 6.283185307179586f * (p0 * fB[j] + p1 * fB[128 + j] + p2 * fB[256 + j]);
    four[b * NDH + j]       = sinf(xp);
    four[b * NDH + 128 + j] = cosf(xp);
}

// ---------------------------------------------------------------- z = vis@img_W + img_b + gelu(four@pos_W + pos_b)
// 64x64 output tile, micro 4x4 per thread, K chunks of 32.
__global__ __launch_bounds__(256) void k_z(
    const float* __restrict__ vis, const float* __restrict__ four,
    const float* __restrict__ img_W, const float* __restrict__ img_b,
    const float* __restrict__ pos_W, const float* __restrict__ pos_b,
    float* __restrict__ z)
{
    __shared__ __align__(16) float A_s[64][33];
    __shared__ __align__(16) float B_s[32][64];
    const int tid = threadIdx.x;
    const int tx4 = (tid & 15) * 4;
    const int ty4 = (tid >> 4) * 4;
    const int ct = blockIdx.x * 64;
    const int rt = blockIdx.y * 64;

    float acc[4][4] = {};
    float acc2[4][4] = {};

    // phase A: vis @ img_W  (K = 1024)
    for (int k0 = 0; k0 < NDVIS; k0 += 32) {
        #pragma unroll
        for (int i = 0; i < 8; i++) {
            int flat = tid + 256 * i;
            int r = flat >> 5, k = flat & 31;
            A_s[r][k] = vis[(rt + r) * NDVIS + k0 + k];
        }
        #pragma unroll
        for (int i = 0; i < 8; i++) {
            int flat = tid + 256 * i;
            int k = flat >> 6, c = flat & 63;
            B_s[k][c] = img_W[(k0 + k) * NDH + ct + c];
        }
        __syncthreads();
        #pragma unroll
        for (int kk = 0; kk < 32; kk++) {
            float a[4];
            #pragma unroll
            for (int i = 0; i < 4; i++) a[i] = A_s[ty4 + i][kk];
            float4 bv = *(const float4*)&B_s[kk][tx4];
            float bb[4] = {bv.x, bv.y, bv.z, bv.w};
            #pragma unroll
            for (int i = 0; i < 4; i++)
                #pragma unroll
                for (int j = 0; j < 4; j++) acc[i][j] += a[i] * bb[j];
        }
        __syncthreads();
    }

    // phase B: four @ pos_W  (K = 256)
    for (int k0 = 0; k0 < NDH; k0 += 32) {
        #pragma unroll
        for (int i = 0; i < 8; i++) {
            int flat = tid + 256 * i;
            int r = flat >> 5, k = flat & 31;
            A_s[r][k] = four[(rt + r) * NDH + k0 + k];
        }
        #pragma unroll
        for (int i = 0; i < 8; i++) {
            int flat = tid + 256 * i;
            int k = flat >> 6, c = flat & 63;
            B_s[k][c] = pos_W[(k0 + k) * NDH + ct + c];
        }
        __syncthreads();
        #pragma unroll
        for (int kk = 0; kk < 32; kk++) {
            float a[4];
            #pragma unroll
            for (int i = 0; i < 4; i++) a[i] = A_s[ty4 + i][kk];
            float4 bv = *(const float4*)&B_s[kk][tx4];
            float bb[4] = {bv.x, bv.y, bv.z, bv.w};
            #pragma unroll
            for (int i = 0; i < 4; i++)
                #pragma unroll
                for (int j = 0; j < 4; j++) acc2[i][j] += a[i] * bb[j];
        }
        __syncthreads();
    }

    #pragma unroll
    for (int i = 0; i < 4; i++) {
        int row = rt + ty4 + i;
        float4 v;
        float* vp = &v.x;
        #pragma unroll
        for (int j = 0; j < 4; j++) {
            int c = ct + tx4 + j;
            vp[j] = acc[i][j] + img_b[c] + gelu_f(acc2[i][j] + pos_b[c]);
        }
        *(float4*)&z[row * NDH + ct + tx4] = v;
    }
}

// ---------------------------------------------------------------- router: top-1 gate + expert index + per-expert counts
// one wave (64 lanes) per row
__global__ __launch_bounds__(256) void k_router(
    const float* __restrict__ z, const float* __restrict__ grad,
    const float* __restrict__ rW, const float* __restrict__ rb,
    float* __restrict__ gate, int* __restrict__ eidx, int* __restrict__ cnt)
{
    const int lane = threadIdx.x & 63;
    const int w = threadIdx.x >> 6;
    const int b = blockIdx.x * 4 + w;
    float l0 = 0.f, l1 = 0.f, l2 = 0.f, l3 = 0.f;
    #pragma unroll
    for (int i = 0; i < 4; i++) {
        int k = lane + 64 * i;
        float zv = z[b * NDH + k];
        float4 rw = *(const float4*)&rW[k * 4];
        l0 += zv * rw.x; l1 += zv * rw.y; l2 += zv * rw.z; l3 += zv * rw.w;
    }
    #pragma unroll
    for (int off = 32; off > 0; off >>= 1) {
        l0 += __shfl_xor(l0, off);
        l1 += __shfl_xor(l1, off);
        l2 += __shfl_xor(l2, off);
        l3 += __shfl_xor(l3, off);
    }
    if (lane == 0) {
        float g = grad[b];
        float l[4];
        l[0] = l0 + g * rW[256 * 4 + 0] + rb[0];
        l[1] = l1 + g * rW[256 * 4 + 1] + rb[1];
        l[2] = l2 + g * rW[256 * 4 + 2] + rb[2];
        l[3] = l3 + g * rW[256 * 4 + 3] + rb[3];
        int bi = 0; float best = l[0];
        #pragma unroll
        for (int e = 1; e < 4; e++) if (l[e] > best) { best = l[e]; bi = e; }
        float s = 0.f;
        #pragma unroll
        for (int e = 0; e < 4; e++) s += expf(l[e] - best);
        gate[b] = 1.0f / s;          // = p_max
        eidx[b] = bi;
        atomicAdd(&cnt[bi], 1);
    }
}

__global__ void k_zero(int* __restrict__ p) {
    if (threadIdx.x < 8) p[threadIdx.x] = 0;   // cnt[0..3], cur[0..3]
}

__global__ void k_offs(const int* __restrict__ cnt, int* __restrict__ offs, int* __restrict__ cur) {
    if (threadIdx.x == 0) {
        int o = 0;
        for (int e = 0; e < NEXP; e++) { offs[e] = o; cur[e] = o; o += cnt[e]; }
    }
}

__global__ __launch_bounds__(256) void k_scatter(const int* __restrict__ eidx,
                                                 int* __restrict__ cur,
                                                 int* __restrict__ list) {
    int b = blockIdx.x * 256 + threadIdx.x;
    int e = eidx[b];
    int p = atomicAdd(&cur[e], 1);
    list[p] = b;
}

// ---------------------------------------------------------------- expert MLP on gathered rows
// zf[row] = z[row] + gate[row] * ( gelu(z[row] @ W1[e] + b1[e]) @ W2[e] + b2[e] )
// block: 32 gathered rows of one expert; 256 threads.
__global__ __launch_bounds__(256) void k_expert(
    const float* __restrict__ z, const float* __restrict__ gate,
    const int* __restrict__ cnt, const int* __restrict__ offs, const int* __restrict__ list,
    const float* __restrict__ W1, const float* __restrict__ b1,
    const float* __restrict__ W2, const float* __restrict__ b2,
    float* __restrict__ zf)
{
    const int e = blockIdx.x;
    const int n0 = blockIdx.y * 32;
    const int ne = cnt[e];
    if (n0 >= ne) return;

    __shared__ __align__(16) float z_s[256][32];   // [k][r]   32 KB
    __shared__ __align__(16) float h_s[128][32];   // [j][r]   16 KB (one 128-wide hidden chunk)
    __shared__ __align__(16) float w_s[4096];      // union: W1 chunk 32x128 / W2 chunk 16x256
    __shared__ int gr[32];

    const int tid = threadIdx.x;
    if (tid < 32) gr[tid] = (n0 + tid < ne) ? list[offs[e] + n0 + tid] : -1;
    __syncthreads();

    // stage z rows transposed: z_s[k][r]
    #pragma unroll 4
    for (int i = 0; i < 32; i++) {
        int row = gr[i];
        z_s[tid][i] = (row >= 0) ? z[row * NDH + tid] : 0.0f;
    }
    __syncthreads();

    const int tx1 = tid & 31, ty1 = tid >> 5;      // GEMM1: 4 j-cols, 4 rows
    const int tx2 = tid & 63, ty2 = tid >> 6;      // GEMM2: 4 c-cols, 8 rows
    float oacc[8][4] = {};

    for (int jc = 0; jc < 8; jc++) {               // hidden dim 1024 in chunks of 128
        // ---- GEMM1: h_chunk = gelu(z @ W1[:, jc*128 : +128] + b1)
        float hacc[4][4] = {};
        for (int kc = 0; kc < 8; kc++) {           // K = 256 in chunks of 32
            __syncthreads();
            #pragma unroll
            for (int i = 0; i < 16; i++) {
                int flat = tid + 256 * i;          // 32 x 128
                int k = flat >> 7, j = flat & 127;
                w_s[k * 128 + j] = W1[(e * NDH + kc * 32 + k) * NHID + jc * 128 + j];
            }
            __syncthreads();
            #pragma unroll
            for (int kk = 0; kk < 32; kk++) {
                float4 av = *(const float4*)&z_s[kc * 32 + kk][ty1 * 4];
                float4 bv = *(const float4*)&w_s[kk * 128 + tx1 * 4];
                float aa[4] = {av.x, av.y, av.z, av.w};
                float bb[4] = {bv.x, bv.y, bv.z, bv.w};
                #pragma unroll
                for (int i = 0; i < 4; i++)
                    #pragma unroll
                    for (int j = 0; j < 4; j++) hacc[i][j] += aa[i] * bb[j];
            }
        }
        __syncthreads();
        #pragma unroll
        for (int j = 0; j < 4; j++) {
            int jl = tx1 * 4 + j;
            float bb1 = b1[e * NHID + jc * 128 + jl];
            float4 hv;
            hv.x = gelu_f(hacc[0][j] + bb1);
            hv.y = gelu_f(hacc[1][j] + bb1);
            hv.z = gelu_f(hacc[2][j] + bb1);
            hv.w = gelu_f(hacc[3][j] + bb1);
            *(float4*)&h_s[jl][ty1 * 4] = hv;
        }
        // ---- GEMM2: oacc += h_chunk @ W2[jc*128 : +128, :]
        for (int kc2 = 0; kc2 < 8; kc2++) {        // 128 in chunks of 16
            __syncthreads();
            #pragma unroll
            for (int i = 0; i < 16; i++) {
                int flat = tid + 256 * i;          // 16 x 256
                int k = flat >> 8, c = flat & 255;
                w_s[k * 256 + c] = W2[(e * NHID + jc * 128 + kc2 * 16 + k) * NDH + c];
            }
            __syncthreads();
            #pragma unroll
            for (int kk = 0; kk < 16; kk++) {
                int kl = kc2 * 16 + kk;
                float4 a0 = *(const float4*)&h_s[kl][ty2 * 8];
                float4 a1 = *(const float4*)&h_s[kl][ty2 * 8 + 4];
                float4 bv = *(const float4*)&w_s[kk * 256 + tx2 * 4];
                float aa[8] = {a0.x, a0.y, a0.z, a0.w, a1.x, a1.y, a1.z, a1.w};
                float bb[4] = {bv.x, bv.y, bv.z, bv.w};
                #pragma unroll
                for (int i = 0; i < 8; i++)
                    #pragma unroll
                    for (int j = 0; j < 4; j++) oacc[i][j] += aa[i] * bb[j];
            }
        }
    }

    // epilogue: zf[row] = z[row] + gate[row] * (oacc + b2)
    #pragma unroll
    for (int i = 0; i < 8; i++) {
        int r = ty2 * 8 + i;
        int row = gr[r];
        if (row < 0) continue;
        float gv = gate[row];
        int c = tx2 * 4;
        float4 zv = *(const float4*)&z[row * NDH + c];
        float4 b2v = *(const float4*)&b2[e * NDH + c];
        float4 res;
        res.x = zv.x + gv * (oacc[i][0] + b2v.x);
        res.y = zv.y + gv * (oacc[i][1] + b2v.y);
        res.z = zv.z + gv * (oacc[i][2] + b2v.z);
        res.w = zv.w + gv * (oacc[i][3] + b2v.w);
        *(float4*)&zf[row * NDH + c] = res;
    }
}

// ---------------------------------------------------------------- gene decoder stage 1: t = gelu(LN(zf @ gd_W1 + gd_b1))
// 16 rows per block; wave w owns rows 4w..4w+3 with all 256 cols across its lanes.
__global__ __launch_bounds__(256) void k_gd1(
    const float* __restrict__ zf, const float* __restrict__ W, const float* __restrict__ bias,
    const float* __restrict__ g, const float* __restrict__ beta, float* __restrict__ t)
{
    __shared__ __align__(16) float A_s[16][33];
    __shared__ __align__(16) float W_s[32 * 256];
    const int tid = threadIdx.x;
    const int tx = tid & 63, ty = tid >> 6;
    const int rt = blockIdx.x * 16;
    float acc[4][4] = {};

    for (int k0 = 0; k0 < NDH; k0 += 32) {
        #pragma unroll
        for (int i = 0; i < 2; i++) {
            int flat = tid + 256 * i;              // 16 x 32
            int r = flat >> 5, k = flat & 31;
            A_s[r][k] = zf[(rt + r) * NDH + k0 + k];
        }
        #pragma unroll
        for (int i = 0; i < 32; i++) {
            int flat = tid + 256 * i;              // 32 x 256
            int k = flat >> 8, c = flat & 255;
            W_s[k * 256 + c] = W[(k0 + k) * NDH + c];
        }
        __syncthreads();
        #pragma unroll
        for (int kk = 0; kk < 32; kk++) {
            float a[4];
            #pragma unroll
            for (int i = 0; i < 4; i++) a[i] = A_s[ty * 4 + i][kk];
            float4 bv = *(const float4*)&W_s[kk * 256 + tx * 4];
            float bb[4] = {bv.x, bv.y, bv.z, bv.w};
            #pragma unroll
            for (int i = 0; i < 4; i++)
                #pragma unroll
                for (int j = 0; j < 4; j++) acc[i][j] += a[i] * bb[j];
        }
        __syncthreads();
    }

    #pragma unroll
    for (int i = 0; i < 4; i++) {
        float v[4];
        #pragma unroll
        for (int j = 0; j < 4; j++) v[j] = acc[i][j] + bias[tx * 4 + j];
        float s1 = v[0] + v[1] + v[2] + v[3];
        float s2 = v[0]*v[0] + v[1]*v[1] + v[2]*v[2] + v[3]*v[3];
        #pragma unroll
        for (int off = 32; off > 0; off >>= 1) {
            s1 += __shfl_xor(s1, off);
            s2 += __shfl_xor(s2, off);
        }
        float mean = s1 * (1.0f / 256.0f);
        float var = s2 * (1.0f / 256.0f) - mean * mean;
        float rstd = rsqrtf(var + 1e-5f);
        int row = rt + ty * 4 + i;
        float4 ov;
        float* op = &ov.x;
        #pragma unroll
        for (int j = 0; j < 4; j++) {
            int c = tx * 4 + j;
            op[j] = gelu_f(g[c] * (v[j] - mean) * rstd + beta[c]);
        }
        *(float4*)&t[row * NDH + tx * 4] = ov;
    }
}

// ---------------------------------------------------------------- gene decoder stage 2 (dominant GEMM):
// preds = t @ gd_W2 + gd_b2 -> mu/theta with softplus epilogue
__global__ __launch_bounds__(256) void k_gd2(
    const float* __restrict__ t, const float* __restrict__ W, const float* __restrict__ bias,
    const float* __restrict__ lib, float* __restrict__ mu_out, float* __restrict__ th_out)
{
    __shared__ __align__(16) float A_s[64][33];
    __shared__ __align__(16) float B_s[32][64];
    const int tid = threadIdx.x;
    const int tx4 = (tid & 15) * 4;
    const int ty4 = (tid >> 4) * 4;
    const int ct = blockIdx.x * 64;        // over 10000 (2*G)
    const int rt = blockIdx.y * 64;
    float acc[4][4] = {};

    for (int k0 = 0; k0 < NDH; k0 += 32) {
        #pragma unroll
        for (int i = 0; i < 8; i++) {
            int flat = tid + 256 * i;
            int r = flat >> 5, k = flat & 31;
            A_s[r][k] = t[(rt + r) * NDH + k0 + k];
        }
        #pragma unroll
        for (int i = 0; i < 8; i++) {
            int flat = tid + 256 * i;
            int k = flat >> 6, c = flat & 63;
            int gc = ct + c;
            B_s[k][c] = (gc < 2 * NGENE) ? W[(k0 + k) * (2 * NGENE) + gc] : 0.0f;
        }
        __syncthreads();
        #pragma unroll
        for (int kk = 0; kk < 32; kk++) {
            float a[4];
            #pragma unroll
            for (int i = 0; i < 4; i++) a[i] = A_s[ty4 + i][kk];
            float4 bv = *(const float4*)&B_s[kk][tx4];
            float bb[4] = {bv.x, bv.y, bv.z, bv.w};
            #pragma unroll
            for (int i = 0; i < 4; i++)
                #pragma unroll
                for (int j = 0; j < 4; j++) acc[i][j] += a[i] * bb[j];
        }
        __syncthreads();
    }

    #pragma unroll
    for (int i = 0; i < 4; i++) {
        int row = rt + ty4 + i;
        float lv = lib[row];
        #pragma unroll
        for (int j = 0; j < 4; j++) {
            int gc = ct + tx4 + j;
            if (gc < 2 * NGENE) {
                float sp = softplus_f(acc[i][j] + bias[gc]);
                int gg = gc >> 1;
                if ((gc & 1) == 0) mu_out[row * NGENE + gg] = sp * lv + 1e-6f;
                else               th_out[row * NGENE + gg] = sp + 1e-6f;
            }
        }
    }
}

// ---------------------------------------------------------------- func + align heads, 8 rows per block
__global__ __launch_bounds__(256) void k_heads(
    const float* __restrict__ zf,
    const float* __restrict__ apW1, const float* __restrict__ apb1,
    const float* __restrict__ apW2, const float* __restrict__ apb2,
    const float* __restrict__ fhW1, const float* __restrict__ fhb1,
    const float* __restrict__ fhW2, const float* __restrict__ fhb2,
    float* __restrict__ func_out, float* __restrict__ align_out)
{
    __shared__ float zs[8][256];
    __shared__ float ah[8][128];
    __shared__ float fh[8][64];
    const int tid = threadIdx.x;
    const int r0 = blockIdx.x * 8;

    #pragma unroll
    for (int i = 0; i < 8; i++) zs[i][tid] = zf[(r0 + i) * NDH + tid];
    __syncthreads();

    if (tid < 128) {
        int j = tid;
        float a[8] = {};
        for (int k = 0; k < 256; k++) {
            float w = apW1[k * 128 + j];
            #pragma unroll
            for (int i = 0; i < 8; i++) a[i] += zs[i][k] * w;
        }
        float bb = apb1[j];
        #pragma unroll
        for (int i = 0; i < 8; i++) ah[i][j] = gelu_f(a[i] + bb);
    } else if (tid < 192) {
        int j = tid - 128;
        float a[8] = {};
        for (int k = 0; k < 256; k++) {
            float w = fhW1[k * 64 + j];
            #pragma unroll
            for (int i = 0; i < 8; i++) a[i] += zs[i][k] * w;
        }
        float bb = fhb1[j];
        #pragma unroll
        for (int i = 0; i < 8; i++) fh[i][j] = gelu_f(a[i] + bb);
    }
    __syncthreads();

    if (tid < 240) {
        int r = tid / 30, j = tid % 30;
        float a = 0.f;
        for (int k = 0; k < 128; k++) a += ah[r][k] * apW2[k * 30 + j];
        align_out[(r0 + r) * NSCVI + j] = a + apb2[j];
    } else if (tid < 248) {
        int r = tid - 240;
        float a = 0.f;
        for (int k = 0; k < 64; k++) a += fh[r][k] * fhW2[k];
        func_out[r0 + r] = sigmoid_f(a + fhb2[0]);
    }
}

// ----------------------------------------------------------------
extern "C" void kernel_launch(void* const* d_in, const int* in_sizes, int n_in,
                              void* d_out, int out_size, void* d_ws, size_t ws_size,
                              hipStream_t stream) {
    const float* vis    = (const float*)d_in[0];
    const float* pos    = (const float*)d_in[1];
    const float* grad   = (const float*)d_in[2];
    const float* lib    = (const float*)d_in[3];
    const float* fB     = (const float*)d_in[4];
    const float* img_W  = (const float*)d_in[5];
    const float* img_b  = (const float*)d_in[6];
    const float* pos_W  = (const float*)d_in[7];
    const float* pos_b  = (const float*)d_in[8];
    const float* rW     = (const float*)d_in[9];
    const float* rb     = (const float*)d_in[10];
    const float* eW1    = (const float*)d_in[11];
    const float* eb1    = (const float*)d_in[12];
    const float* eW2    = (const float*)d_in[13];
    const float* eb2    = (const float*)d_in[14];
    const float* gdW1   = (const float*)d_in[15];
    const float* gdb1   = (const float*)d_in[16];
    const float* gdg    = (const float*)d_in[17];
    const float* gdbeta = (const float*)d_in[18];
    const float* gdW2   = (const float*)d_in[19];
    const float* gdb2   = (const float*)d_in[20];
    const float* apW1   = (const float*)d_in[21];
    const float* apb1   = (const float*)d_in[22];
    const float* apW2   = (const float*)d_in[23];
    const float* apb2   = (const float*)d_in[24];
    const float* fhW1   = (const float*)d_in[25];
    const float* fhb1   = (const float*)d_in[26];
    const float* fhW2   = (const float*)d_in[27];
    const float* fhb2   = (const float*)d_in[28];

    char* ws = (char*)d_ws;
    int* cnt  = (int*)(ws + 0);     // 4 ints
    int* cur  = (int*)(ws + 16);    // 4 ints
    int* offs = (int*)(ws + 32);    // 4 ints
    size_t o = 256;
    float* gate = (float*)(ws + o); o += (size_t)NB * 4;
    int*   eidx = (int*)(ws + o);   o += (size_t)NB * 4;
    int*   list = (int*)(ws + o);   o += (size_t)NB * 4;
    float* z    = (float*)(ws + o); o += (size_t)NB * NDH * 4;
    float* zf   = (float*)(ws + o); o += (size_t)NB * NDH * 4;
    float* t    = (float*)(ws + o); o += (size_t)NB * NDH * 4;
    float* four = (float*)(ws + o); o += (size_t)NB * NDH * 4;

    float* out       = (float*)d_out;
    float* mu_out    = out;
    float* th_out    = out + (size_t)NB * NGENE;
    float* func_out  = out + (size_t)2 * NB * NGENE;
    float* align_out = func_out + NB;

    k_zero<<<1, 64, 0, stream>>>(cnt);
    k_four<<<NB * 128 / 256, 256, 0, stream>>>(pos, fB, four);
    k_z<<<dim3(4, 256), 256, 0, stream>>>(vis, four, img_W, img_b, pos_W, pos_b, z);
    k_router<<<NB / 4, 256, 0, stream>>>(z, grad, rW, rb, gate, eidx, cnt);
    k_offs<<<1, 64, 0, stream>>>(cnt, offs, cur);
    k_scatter<<<NB / 256, 256, 0, stream>>>(eidx, cur, list);
    k_expert<<<dim3(NEXP, NB / 32), 256, 0, stream>>>(z, gate, cnt, offs, list,
                                                      eW1, eb1, eW2, eb2, zf);
    k_gd1<<<NB / 16, 256, 0, stream>>>(zf, gdW1, gdb1, gdg, gdbeta, t);
    k_gd2<<<dim3(157, 256), 256, 0, stream>>>(t, gdW2, gdb2, lib, mu_out, th_out);
    k_heads<<<NB / 8, 256, 0, stream>>>(zf, apW1, apb1, apW2, apb2,
                                        fhW1, fhb1, fhW2, fhb2, func_out, align_out);
}